// Round 1
// baseline (114.779 us; speedup 1.0000x reference)
//
#include <hip/hip_runtime.h>

// RippleLinear: out[b,o] = sum_i amp[i,o] * sin(x[b,i]*freq[i,o] + ph[i,o]) + bias0[o]
//   x:      (2048, 256) f32   (16*128 rows)
//   weight: (256, 256, 2) f32  -> amp = w[i][o][0], freq = w[i][o][1]
//   bias:   (257, 256) f32     -> bias0 = bias[0][:], ph[i][o] = bias[1+i][o]
//   out:    (2048, 256) f32
//
// Structure: thread = one output column o (256 threads/block, coalesced float2
// weight loads); block = BTILE batch rows (x reads are block-uniform -> scalar
// loads); 256 blocks over 256 CUs. Compute-bound on v_sin_f32.

constexpr int IN_F  = 256;
constexpr int OUT_F = 256;
constexpr int BROWS = 2048;
constexpr int BTILE = 8;

__global__ __launch_bounds__(256) void ripple_kernel(
    const float* __restrict__ x,       // (BROWS, IN_F)
    const float* __restrict__ weight,  // (IN_F, OUT_F, 2)
    const float* __restrict__ bias,    // (IN_F+1, OUT_F)
    float* __restrict__ out)           // (BROWS, OUT_F)
{
    const int o  = threadIdx.x;            // 0..255, output column
    const int b0 = blockIdx.x * BTILE;     // batch-row base

    float acc[BTILE];
#pragma unroll
    for (int r = 0; r < BTILE; ++r) acc[r] = 0.0f;

    const float2* __restrict__ w2 = (const float2*)weight;  // (amp,freq) pairs

    for (int i = 0; i < IN_F; ++i) {
        const float2 w  = w2[i * OUT_F + o];          // coalesced 8B/lane
        const float  ph = bias[(i + 1) * OUT_F + o];  // coalesced 4B/lane

        // x values are uniform across the block -> scalar loads
        float xv[BTILE];
#pragma unroll
        for (int r = 0; r < BTILE; ++r)
            xv[r] = x[(b0 + r) * IN_F + i];

#pragma unroll
        for (int r = 0; r < BTILE; ++r)
            acc[r] += w.x * __sinf(fmaf(xv[r], w.y, ph));
    }

    const float bo = bias[o];
#pragma unroll
    for (int r = 0; r < BTILE; ++r)
        out[(b0 + r) * OUT_F + o] = acc[r] + bo;
}

extern "C" void kernel_launch(void* const* d_in, const int* in_sizes, int n_in,
                              void* d_out, int out_size, void* d_ws, size_t ws_size,
                              hipStream_t stream) {
    const float* x      = (const float*)d_in[0];
    const float* weight = (const float*)d_in[1];
    const float* bias   = (const float*)d_in[2];
    float* out          = (float*)d_out;

    dim3 grid(BROWS / BTILE);   // 256 blocks
    dim3 block(256);
    ripple_kernel<<<grid, block, 0, stream>>>(x, weight, bias, out);
}

// Round 2
// 98.722 us; speedup vs baseline: 1.1627x; 1.1627x over previous
//
#include <hip/hip_runtime.h>

// RippleLinear: out[b,o] = sum_i amp[i,o] * sin(x[b,i]*freq[i,o] + ph[i,o]) + bias0[o]
//   x:      (2048, 256) f32   (16*128 rows)
//   weight: (256, 256, 2) f32  -> amp = w[i][o][0], freq = w[i][o][1]
//   bias:   (257, 256) f32     -> bias0 = bias[0][:], ph[i][o] = bias[1+i][o]
//   out:    (2048, 256) f32
//
// R1 -> R2: was 1 block/CU (4 waves/CU, OccupancyPercent 10.8, VALUBusy 19%)
// -> latency-bound. Keep grid=256 & BTILE=8 (weight re-stream stays 192 MB of
// L2 traffic ~5.6us) but split the i-reduction 4-way inside a 1024-thread
// block: waves/CU 4 -> 16 with no extra global traffic. LDS cross-group
// reduction (24 KB) at the end.

constexpr int IN_F   = 256;
constexpr int OUT_F  = 256;
constexpr int BROWS  = 2048;
constexpr int BTILE  = 8;   // batch rows per block
constexpr int ISPLIT = 4;   // i-dimension split inside the block
constexpr int ICHUNK = IN_F / ISPLIT;  // 64 i per group

__global__ __launch_bounds__(OUT_F * ISPLIT) void ripple_kernel(
    const float* __restrict__ x,       // (BROWS, IN_F)
    const float* __restrict__ weight,  // (IN_F, OUT_F, 2)
    const float* __restrict__ bias,    // (IN_F+1, OUT_F)
    float* __restrict__ out)           // (BROWS, OUT_F)
{
    const int o  = threadIdx.x;            // 0..255, output column
    const int g  = threadIdx.y;            // 0..3, i-group
    const int b0 = blockIdx.x * BTILE;     // batch-row base

    float acc[BTILE];
#pragma unroll
    for (int r = 0; r < BTILE; ++r) acc[r] = 0.0f;

    const float2* __restrict__ w2 = (const float2*)weight;  // (amp,freq) pairs

    const int i0 = g * ICHUNK;
#pragma unroll 2
    for (int ii = 0; ii < ICHUNK; ++ii) {
        const int i = i0 + ii;
        const float2 w  = w2[i * OUT_F + o];          // coalesced 8B/lane
        const float  ph = bias[(i + 1) * OUT_F + o];  // coalesced 4B/lane

        // x values are block-uniform -> scalar loads
        float xv[BTILE];
#pragma unroll
        for (int r = 0; r < BTILE; ++r)
            xv[r] = x[(b0 + r) * IN_F + i];

#pragma unroll
        for (int r = 0; r < BTILE; ++r)
            acc[r] += w.x * __sinf(fmaf(xv[r], w.y, ph));
    }

    // cross-group reduction: groups 1..3 park partials in LDS, group 0 sums.
    __shared__ float red[ISPLIT - 1][BTILE][OUT_F];  // 24 KB
    if (g > 0) {
#pragma unroll
        for (int r = 0; r < BTILE; ++r) red[g - 1][r][o] = acc[r];
    }
    __syncthreads();
    if (g == 0) {
        const float bo = bias[o];
#pragma unroll
        for (int r = 0; r < BTILE; ++r) {
            float s = acc[r];
#pragma unroll
            for (int gg = 0; gg < ISPLIT - 1; ++gg) s += red[gg][r][o];
            out[(b0 + r) * OUT_F + o] = s + bo;
        }
    }
}

extern "C" void kernel_launch(void* const* d_in, const int* in_sizes, int n_in,
                              void* d_out, int out_size, void* d_ws, size_t ws_size,
                              hipStream_t stream) {
    const float* x      = (const float*)d_in[0];
    const float* weight = (const float*)d_in[1];
    const float* bias   = (const float*)d_in[2];
    float* out          = (float*)d_out;

    dim3 grid(BROWS / BTILE);        // 256 blocks
    dim3 block(OUT_F, ISPLIT);       // 1024 threads
    ripple_kernel<<<grid, block, 0, stream>>>(x, weight, bias, out);
}